// Round 3
// baseline (149.326 us; speedup 1.0000x reference)
//
#include <hip/hip_runtime.h>

// Gabor atom renderer: out[idx] += amp * exp(-0.5*((t-tau)/sigma)^2)
//                                      * cos(2*pi*(omega*dt + 0.5*gamma*dt^2) + phi)
// for |dt| <= 5*sigma, idx in [0, num_samples).
//
// Round 3 == round 2 resubmitted (round 2 was a GPU-acquisition timeout,
// kernel never ran): precision-critical chain (t, dt, phase, mod-1
// reduction) in f64 — the f32 rounding of t=idx/24000 alone is worth up to
// ~0.05 rad of phase at omega=8kHz, the dominant error vs the (f64) numpy
// reference. cos evaluated on the exactly-reduced argument with a
// quadrant-split f32 Taylor polynomial (abs err ~3e-7; hw v_cos_f32 ~2^-12).

constexpr double SR_D      = 24000.0;
constexpr double INV_SR_D  = 1.0 / 24000.0;          // 2-ulp from true idx/SR: irrelevant
constexpr double INV_2PI_D = 0.15915494309189535;    // 1/(2*pi)
constexpr int    HALF_MAX  = 1201;

// cos(2*pi*m) for m in [-0.5, 0.5]. Quadrant split; Taylor on [-pi/4, pi/4].
__device__ __forceinline__ float cos2pi(float m)
{
    float qf  = rintf(4.0f * m);          // quadrant, in {-2,-1,0,1,2}
    float rem = fmaf(qf, -0.25f, m);      // in [-0.125, 0.125], (near-)exact
    float th  = 6.28318530717958647f * rem;  // in [-pi/4, pi/4]
    float t2  = th * th;
    // sin(th): err ~ th^9/362880 <= 3.1e-7
    float s = th * fmaf(t2, fmaf(t2, fmaf(t2, -1.98412701e-4f, 8.33333377e-3f),
                                  -0.166666672f), 1.0f);
    // cos(th): err ~ th^10/3628800 <= 2.5e-8
    float c = fmaf(t2, fmaf(t2, fmaf(t2, fmaf(t2, 2.48015876e-5f, -1.38888892e-3f),
                                     4.16666679e-2f), -0.5f), 1.0f);
    int qm = ((int)qf) & 3;               // cos(th + q*pi/2)
    float r = (qm == 0) ? c : (qm == 1) ? -s : (qm == 2) ? -c : s;
    return r;
}

__global__ __launch_bounds__(256)
void gabor_scatter(const float* __restrict__ amp,
                   const float* __restrict__ tau,
                   const float* __restrict__ omg,
                   const float* __restrict__ sig,
                   const float* __restrict__ phi,
                   const float* __restrict__ gam,
                   float* __restrict__ out,
                   int num_samples)
{
    const int atom = blockIdx.x;
    const float  a    = amp[atom];
    const double tu   = (double)tau[atom];
    const double om   = (double)omg[atom];
    const double sg   = (double)sig[atom];
    const double phr  = (double)phi[atom] * INV_2PI_D;  // phase in revolutions
    const double gm_h = 0.5 * (double)gam[atom];

    const int center = (int)rint(tu * SR_D);

    const double sm     = 5.0 * sg;                  // exact (sg is f32)
    const double inv_sg = 1.0 / sg;

    // sigma-culled half width (conservative): |dt|<=5sg only possible within
    // 5*sg*SR + 0.5 samples of center.
    int hw = (int)ceil(sm * SR_D) + 1;
    hw = min(hw, HALF_MAX);
    int lo = max(center - hw, 0);
    int hi = min(center + hw, num_samples - 1);

    for (int idx = lo + (int)threadIdx.x; idx <= hi; idx += 256) {
        double t  = (double)idx * INV_SR_D;
        double dt = t - tu;
        if (fabs(dt) <= sm) {
            // envelope: arg in f64, one fast exp (relative err ~1e-6, harmless)
            double z   = dt * inv_sg;
            float  env = __expf((float)(-0.5 * z * z));
            // phase in revolutions, f64 (|r|<=~401, f64 keeps ~5e-14)
            double r = om * dt + gm_h * dt * dt + phr;
            double f = r - floor(r);          // [0,1), exact
            float  m = (float)(f - 0.5);      // [-0.5,0.5], ulp 6e-8 -> 3.7e-7 rad
            float  c = -cos2pi(m);            // cos(2*pi*f)
            atomicAdd(&out[idx], a * env * c);
        }
    }
}

extern "C" void kernel_launch(void* const* d_in, const int* in_sizes, int n_in,
                              void* d_out, int out_size, void* d_ws, size_t ws_size,
                              hipStream_t stream)
{
    const float* amp = (const float*)d_in[0];
    const float* tau = (const float*)d_in[1];
    const float* omg = (const float*)d_in[2];
    const float* sig = (const float*)d_in[3];
    const float* phi = (const float*)d_in[4];
    const float* gam = (const float*)d_in[5];
    const int N = in_sizes[0];            // 16384 atoms
    float* out = (float*)d_out;           // num_samples == out_size

    // d_out is poisoned with 0xAA before every timed call -> zero it first.
    hipMemsetAsync(out, 0, (size_t)out_size * sizeof(float), stream);

    gabor_scatter<<<N, 256, 0, stream>>>(amp, tau, omg, sig, phi, gam,
                                         out, out_size);
}

// Round 4
// 136.706 us; speedup vs baseline: 1.0923x; 1.0923x over previous
//
#include <hip/hip_runtime.h>

// Gabor renderer, round 4: binned gather (atomic-free hot loop).
//   Phase A: bin atoms into per-output-tile lists (tiny atomic traffic, ~98K adds).
//   Phase B: one block per 256-sample tile; atom params staged in LDS; each
//            thread accumulates its sample in a register; one coalesced store.
// Round-3 scatter showed WRITE_SIZE=93MB (= 1 write-through per atomicAdd),
// VALUBusy 31% -> atomic-RMW bound. Gather removes 97% of memory-side traffic.
// Numerics identical to the passing round-3 kernel: f64 phase chain (f32
// t=idx/24000 rounding alone is ~0.05 rad @8kHz), quadrant-split poly cos.

constexpr double SR_D       = 24000.0;
constexpr double INV_SR_D   = 1.0 / 24000.0;
constexpr double INV_2PI_D  = 0.15915494309189535;
constexpr int    HALF_MAX   = 1201;  // ceil(5*0.01*24000)+1
constexpr int    TILE_SHIFT = 8;
constexpr int    TILE       = 1 << TILE_SHIFT;   // 256 samples per tile
constexpr int    CAP        = 256;               // per-tile atom capacity (mean ~99)

// cos(2*pi*m) for m in [-0.5, 0.5]. Quadrant split; Taylor on [-pi/4, pi/4].
__device__ __forceinline__ float cos2pi(float m)
{
    float qf  = rintf(4.0f * m);
    float rem = fmaf(qf, -0.25f, m);          // [-0.125, 0.125]
    float th  = 6.28318530717958647f * rem;   // [-pi/4, pi/4]
    float t2  = th * th;
    float s = th * fmaf(t2, fmaf(t2, fmaf(t2, -1.98412701e-4f, 8.33333377e-3f),
                                  -0.166666672f), 1.0f);
    float c = fmaf(t2, fmaf(t2, fmaf(t2, fmaf(t2, 2.48015876e-5f, -1.38888892e-3f),
                                     4.16666679e-2f), -0.5f), 1.0f);
    int qm = ((int)qf) & 3;
    return (qm == 0) ? c : (qm == 1) ? -s : (qm == 2) ? -c : s;
}

// ---------------- Phase A: bin atoms to tiles ----------------
__global__ __launch_bounds__(256)
void bin_atoms(const float* __restrict__ tau, const float* __restrict__ sig,
               int* __restrict__ counts, int* __restrict__ lists,
               int num_samples, int n_atoms)
{
    int atom = blockIdx.x * 256 + threadIdx.x;
    if (atom >= n_atoms) return;
    double tu = (double)tau[atom];
    double sg = (double)sig[atom];
    int center = (int)rint(tu * SR_D);
    int hw = (int)ceil(5.0 * sg * SR_D) + 1;
    hw = min(hw, HALF_MAX);
    int lo = max(center - hw, 0);
    int hi = min(center + hw, num_samples - 1);
    if (lo > hi) return;
    int t0 = lo >> TILE_SHIFT, t1 = hi >> TILE_SHIFT;
    for (int t = t0; t <= t1; ++t) {
        int slot = atomicAdd(&counts[t], 1);
        if (slot < CAP) lists[t * CAP + slot] = atom;
    }
}

// ---------------- Phase B: gather per tile ----------------
__global__ __launch_bounds__(256)
void gather_tile(const float* __restrict__ amp, const float* __restrict__ tau,
                 const float* __restrict__ omg, const float* __restrict__ sig,
                 const float* __restrict__ phi, const float* __restrict__ gam,
                 const int* __restrict__ counts, const int* __restrict__ lists,
                 float* __restrict__ out, int num_samples)
{
    __shared__ double s_tau[CAP];   // f64 params staged once per tile
    __shared__ double s_om [CAP];
    __shared__ double s_phr[CAP];   // phi / (2*pi)
    __shared__ double s_gmh[CAP];   // 0.5 * gamma
    __shared__ float  s_amp[CAP];
    __shared__ float  s_isg[CAP];   // 1/sigma (f32: only feeds the envelope)
    __shared__ float  s_smf[CAP];   // 5*sigma window bound

    const int tile = blockIdx.x;
    const int tid  = threadIdx.x;
    const int cnt  = min(counts[tile], CAP);

    for (int i = tid; i < cnt; i += 256) {
        int a = lists[tile * CAP + i];
        s_tau[i] = (double)tau[a];
        s_om [i] = (double)omg[a];
        s_phr[i] = (double)phi[a] * INV_2PI_D;
        s_gmh[i] = 0.5 * (double)gam[a];
        s_amp[i] = amp[a];
        float sg = sig[a];
        s_isg[i] = 1.0f / sg;
        s_smf[i] = 5.0f * sg;
    }
    __syncthreads();

    const int    idx = (tile << TILE_SHIFT) + tid;
    const double t   = (double)idx * INV_SR_D;
    float acc = 0.0f;

    for (int i = 0; i < cnt; ++i) {
        double dt  = t - s_tau[i];            // exact-enough: f64 kills t-rounding
        float  dtf = (float)dt;
        if (fabsf(dtf) <= s_smf[i]) {
            float z   = dtf * s_isg[i];
            float env = __expf(-0.5f * z * z);
            double r  = fma(s_om[i], dt, s_phr[i]);
            r = fma(s_gmh[i], dt * dt, r);    // revolutions, |r| <= ~401
            double f = r - floor(r);          // [0,1) exact
            float  m = (float)(f - 0.5);
            float  c = -cos2pi(m);            // cos(2*pi*f)
            acc = fmaf(s_amp[i] * env, c, acc);
        }
    }
    if (idx < num_samples) out[idx] = acc;
}

// ---------------- Fallback: round-3 atomic scatter (if ws too small) ----------------
__global__ __launch_bounds__(256)
void gabor_scatter(const float* __restrict__ amp, const float* __restrict__ tau,
                   const float* __restrict__ omg, const float* __restrict__ sig,
                   const float* __restrict__ phi, const float* __restrict__ gam,
                   float* __restrict__ out, int num_samples)
{
    const int atom = blockIdx.x;
    const float  a    = amp[atom];
    const double tu   = (double)tau[atom];
    const double om   = (double)omg[atom];
    const double sg   = (double)sig[atom];
    const double phr  = (double)phi[atom] * INV_2PI_D;
    const double gm_h = 0.5 * (double)gam[atom];
    const int center = (int)rint(tu * SR_D);
    const double sm = 5.0 * sg;
    const double inv_sg = 1.0 / sg;
    int hw = (int)ceil(sm * SR_D) + 1;
    hw = min(hw, HALF_MAX);
    int lo = max(center - hw, 0);
    int hi = min(center + hw, num_samples - 1);
    for (int idx = lo + (int)threadIdx.x; idx <= hi; idx += 256) {
        double t  = (double)idx * INV_SR_D;
        double dt = t - tu;
        if (fabs(dt) <= sm) {
            double z   = dt * inv_sg;
            float  env = __expf((float)(-0.5 * z * z));
            double r = om * dt + gm_h * dt * dt + phr;
            double f = r - floor(r);
            float  m = (float)(f - 0.5);
            float  c = -cos2pi(m);
            atomicAdd(&out[idx], a * env * c);
        }
    }
}

extern "C" void kernel_launch(void* const* d_in, const int* in_sizes, int n_in,
                              void* d_out, int out_size, void* d_ws, size_t ws_size,
                              hipStream_t stream)
{
    const float* amp = (const float*)d_in[0];
    const float* tau = (const float*)d_in[1];
    const float* omg = (const float*)d_in[2];
    const float* sig = (const float*)d_in[3];
    const float* phi = (const float*)d_in[4];
    const float* gam = (const float*)d_in[5];
    const int N = in_sizes[0];            // 16384 atoms
    float* out = (float*)d_out;           // num_samples == out_size

    const int n_tiles     = (out_size + TILE - 1) >> TILE_SHIFT;       // 938
    const size_t cnt_pad  = ((size_t)n_tiles * 4 + 255) & ~(size_t)255;
    const size_t ws_need  = cnt_pad + (size_t)n_tiles * CAP * 4;       // ~964 KB

    if (ws_size >= ws_need) {
        int* counts = (int*)d_ws;
        int* lists  = (int*)((char*)d_ws + cnt_pad);
        // ws is re-poisoned 0xAA before every timed call -> zero counts each call
        hipMemsetAsync(counts, 0, cnt_pad, stream);
        bin_atoms<<<(N + 255) / 256, 256, 0, stream>>>(tau, sig, counts, lists,
                                                       out_size, N);
        gather_tile<<<n_tiles, 256, 0, stream>>>(amp, tau, omg, sig, phi, gam,
                                                 counts, lists, out, out_size);
        // no out memset needed: every sample written exactly once by gather_tile
    } else {
        hipMemsetAsync(out, 0, (size_t)out_size * sizeof(float), stream);
        gabor_scatter<<<N, 256, 0, stream>>>(amp, tau, omg, sig, phi, gam,
                                             out, out_size);
    }
}